// Round 8
// baseline (1636.520 us; speedup 1.0000x reference)
//
#include <hip/hip_runtime.h>

#define NN 16384
#define DL 64
#define HD 128
#define BMW 32          // i-rows per wave
#define BM 128          // rows per WG (4 waves x 32)
#define BN 64           // j per iteration
#define JS 8            // j splits -> grid 128 x 8 = 1024 WGs
#define JCH (NN / JS)
#define NITER (JCH / BN)

typedef _Float16 v8h __attribute__((ext_vector_type(8)));
typedef __fp16 v2fp16 __attribute__((ext_vector_type(2)));
typedef float v16f __attribute__((ext_vector_type(16)));
typedef unsigned short ushort_t;
typedef unsigned int uint32;

__device__ __forceinline__ float bf2f(ushort_t v) {
  return __uint_as_float(((uint32)v) << 16);
}
__device__ __forceinline__ ushort_t f2bf(float f) {
  uint32 u = __float_as_uint(f);
  return (ushort_t)((u + 0x7FFFu + ((u >> 16) & 1u)) >> 16);
}
__device__ __forceinline__ uint32 pack2h(float a, float b) {
  union { v2fp16 h; uint32 u; } p;
  p.h = __builtin_amdgcn_cvt_pkrtz(a, b);
  return p.u;
}
__device__ __forceinline__ void gld16(void* lds, const void* gp) {
  __builtin_amdgcn_global_load_lds(
      (const __attribute__((address_space(1))) uint32*)gp,
      (__attribute__((address_space(3))) uint32*)lds, 16, 0, 0);
}

// ---------------------------------------------------------------------------
// detect input dtype (bf16 vs fp32) from feat bit patterns; stash scalars.
// consts: [0]=isbf, [1]=t, [2]=th, [3]=s2
// ---------------------------------------------------------------------------
__global__ void detect_k(const void* __restrict__ feat,
                         const void* __restrict__ temp,
                         const void* __restrict__ theta,
                         float* __restrict__ consts) {
  const int l = threadIdx.x;  // 64 threads
  const ushort_t* u = (const ushort_t*)feat;
  float v0 = fabsf(bf2f(u[2 * l]));
  float v1 = fabsf(bf2f(u[2 * l + 1]));
  int ok = ((v0 > 1e-4f && v0 < 16.0f) ? 1 : 0) +
           ((v1 > 1e-4f && v1 < 16.0f) ? 1 : 0);
#pragma unroll
  for (int off = 1; off < 64; off <<= 1) ok += __shfl_xor(ok, off, 64);
  if (l == 0) {
    int isbf = (ok >= 100) ? 1 : 0;
    float tv, th;
    if (isbf) {
      tv = bf2f(((const ushort_t*)temp)[0]);
      th = bf2f(((const ushort_t*)theta)[0]);
    } else {
      tv = ((const float*)temp)[0];
      th = ((const float*)theta)[0];
    }
    consts[0] = (float)isbf;
    consts[1] = 1.0f + tv;
    consts[2] = 5.0f + th;
    consts[3] = 2.0f * (1.0f + tv) * 1.44269504088896341f;
  }
}

// ---------------------------------------------------------------------------
// prep: g = relu(x@glw+glb) (fp16), hT = (x@gnw+gnb)^T (fp16 [128][N]),
//       crow = (0.5*th - t*sq)*log2e, crow2 = -crow in MFMA r-order.
// One wave per row. gnn columns paired (2l, 2l+1) for vector weight loads.
// ---------------------------------------------------------------------------
template <int L0>
__global__ __launch_bounds__(256) void prep_k(
    const void* __restrict__ xb, const float* __restrict__ msgp,
    const float* __restrict__ denp, const void* __restrict__ glw,
    const void* __restrict__ glb, const void* __restrict__ gnw,
    const void* __restrict__ gnb, const float* __restrict__ cst,
    _Float16* __restrict__ g, _Float16* __restrict__ hT,
    float* __restrict__ crow, float* __restrict__ crow2) {
  __shared__ float xr[4][128];
  const int w = threadIdx.x >> 6, l = threadIdx.x & 63;
  const int row = blockIdx.x * 4 + w;
  const int isbf = (cst[0] != 0.0f);
  float x0, x1;
  if (L0) {
    if (isbf) {
      const ushort_t* p = (const ushort_t*)xb;
      x0 = bf2f(p[row * 128 + 2 * l]);
      x1 = bf2f(p[row * 128 + 2 * l + 1]);
    } else {
      const float* p = (const float*)xb;
      x0 = p[row * 128 + 2 * l];
      x1 = p[row * 128 + 2 * l + 1];
    }
  } else {
    float m0 = 0.0f, m1 = 0.0f, d = 0.0f;
#pragma unroll
    for (int js = 0; js < JS; ++js) {
      const float* mp = msgp + (size_t)js * NN * HD + (size_t)row * HD;
      m0 += mp[2 * l];
      m1 += mp[2 * l + 1];
      d += denp[js * NN + row];
    }
    float rd = __builtin_amdgcn_rcpf(fmaxf(d, 1e-10f));
    x0 = fmaxf(m0 * rd, 0.0f);
    x1 = fmaxf(m1 * rd, 0.0f);
  }
  xr[w][2 * l] = x0;
  xr[w][2 * l + 1] = x1;
  __syncthreads();
  float ag = 0.0f, a0 = 0.0f, a1 = 0.0f;
  float bg, b0, b1;
  if (isbf) {
    const ushort_t* Wg = (const ushort_t*)glw;
    const uint32* Wn2 = (const uint32*)gnw;  // bf16 pairs: cols 2l,2l+1
#pragma unroll 8
    for (int k = 0; k < 128; ++k) {
      float xk = xr[w][k];
      ag = fmaf(xk, bf2f(Wg[k * 64 + l]), ag);
      uint32 wp = Wn2[k * 64 + l];
      a0 = fmaf(xk, bf2f((ushort_t)(wp & 0xFFFFu)), a0);
      a1 = fmaf(xk, bf2f((ushort_t)(wp >> 16)), a1);
    }
    bg = bf2f(((const ushort_t*)glb)[l]);
    uint32 bp = ((const uint32*)gnb)[l];
    b0 = bf2f((ushort_t)(bp & 0xFFFFu));
    b1 = bf2f((ushort_t)(bp >> 16));
  } else {
    const float* Wg = (const float*)glw;
    const float2* Wn2 = (const float2*)gnw;  // cols 2l,2l+1
#pragma unroll 8
    for (int k = 0; k < 128; ++k) {
      float xk = xr[w][k];
      ag = fmaf(xk, Wg[k * 64 + l], ag);
      float2 wp = Wn2[k * 64 + l];
      a0 = fmaf(xk, wp.x, a0);
      a1 = fmaf(xk, wp.y, a1);
    }
    bg = ((const float*)glb)[l];
    float2 bp = ((const float2*)gnb)[l];
    b0 = bp.x;
    b1 = bp.y;
  }
  const float t = cst[1];
  const float th = cst[2];
  float gv = fmaxf(ag + bg, 0.0f);
  _Float16 gq = (_Float16)gv;
  g[(size_t)row * DL + l] = gq;
  float gf = (float)gq;
  float sq = gf * gf;
#pragma unroll
  for (int off = 1; off < 64; off <<= 1) sq += __shfl_xor(sq, off, 64);
  if (l == 0) {
    float cr = (0.5f * th - t * sq) * 1.44269504088896341f;
    crow[row] = cr;
    // r-order: j_in_group = (q&3) + 8*(q>>2) + 4*hb  =>  invert:
    int jg = row & 31;
    int hb2 = (jg >> 2) & 1;
    int q = (jg & 3) + 4 * (jg >> 3);
    crow2[(row >> 5) * 32 + hb2 * 16 + q] = -cr;
  }
  hT[(size_t)(2 * l) * NN + row] = (_Float16)(a0 + b0);
  hT[(size_t)(2 * l + 1) * NN + row] = (_Float16)(a1 + b1);
}

// ---------------------------------------------------------------------------
// fused sigmoid-attention: msgp[js] = P*H, denp[js] = P*1, P = 256*sigmoid.
// BMW=32; dbuf LDS staging incl. crow2 chunk; sigmoid: rcp(2^(-a-8)+2^-8).
// ---------------------------------------------------------------------------
__global__ __launch_bounds__(256, 3) void attn_main(
    const _Float16* __restrict__ g, const _Float16* __restrict__ hT,
    const float* __restrict__ crow, const float* __restrict__ crow2,
    const float* __restrict__ cst, float* __restrict__ msgp,
    float* __restrict__ denp) {
  // per buffer: Gs 8KB + Hs 16KB; x2 buffers; + crow2 chunks 2x256B
  __shared__ __align__(16) short SM[2 * 12288];
  __shared__ __align__(16) float SMc[2][64];

  const int tid = threadIdx.x;
  const int w = tid >> 6;
  const int l = tid & 63;
  const int ln = l & 31;
  const int hb = l >> 5;
  const int iw = blockIdx.x * BM + w * BMW;
  const int jb = blockIdx.y * JCH;
  const float negs2 = -cst[3];

  // persistent B-operand frags of G_i: B[n=i=lane&31][k=kf*16+hb*8+e]
  v8h Bi[4];
#pragma unroll
  for (int kf = 0; kf < 4; ++kf)
    Bi[kf] = *(const v8h*)(g + (size_t)(iw + ln) * DL + kf * 16 + hb * 8);

  const float cin = -crow[iw + ln] - 8.0f;

  v16f o[4];
#pragma unroll
  for (int mp = 0; mp < 4; ++mp)
#pragma unroll
    for (int r = 0; r < 16; ++r) o[mp][r] = 0.0f;

  float dp = 0.0f;

  auto stage = [&](int p, int j0) {
    char* Gb = (char*)(SM + p * 12288);
    char* Hb = (char*)(SM + p * 12288 + 4096);
#pragma unroll
    for (int oo = 0; oo < 2; ++oo) {
      int c = oo * 256 + tid;
      int jj = c >> 3, pc = c & 7;
      int kc = pc ^ (jj & 7);
      gld16(Gb + (oo * 256 + w * 64) * 16, g + (size_t)(j0 + jj) * DL + kc * 8);
    }
#pragma unroll
    for (int oo = 0; oo < 4; ++oo) {
      int c = oo * 256 + tid;
      int hc = c >> 3, pc = c & 7;
      int jc = pc ^ (hc & 7);
      gld16(Hb + (oo * 256 + w * 64) * 16, hT + (size_t)hc * NN + j0 + jc * 8);
    }
    if (tid < 64) SMc[p][tid] = crow2[j0 + tid];  // wave-0 coalesced + ds_write
  };

  stage(0, jb);

#pragma unroll 1
  for (int itr = 0; itr < NITER; ++itr) {
    const int j0 = jb + itr * BN;
    const int p = itr & 1;
    __syncthreads();  // drains loads issued a full compute-phase ago
    if (itr + 1 < NITER) stage(p ^ 1, j0 + BN);
    _Float16* Gs = (_Float16*)(SM + p * 12288);
    _Float16* Hs = (_Float16*)(SM + p * 12288 + 4096);
    const float* cb = SMc[p];

#pragma unroll
    for (int jt = 0; jt < 2; ++jt) {
      float cjn[16];  // broadcast ds_read_b128 x4 (r-ordered, negated)
#pragma unroll
      for (int q2 = 0; q2 < 4; ++q2) {
        float4 f4 = *(const float4*)(cb + jt * 32 + hb * 16 + q2 * 4);
        cjn[q2 * 4 + 0] = f4.x;
        cjn[q2 * 4 + 1] = f4.y;
        cjn[q2 * 4 + 2] = f4.z;
        cjn[q2 * 4 + 3] = f4.w;
      }
      // S^T = G_j * G_i^T
      v16f sv;
#pragma unroll
      for (int r = 0; r < 16; ++r) sv[r] = 0.0f;
#pragma unroll
      for (int kf = 0; kf < 4; ++kf) {
        int row = jt * 32 + ln;
        int kc = kf * 2 + hb;
        v8h a = *(const v8h*)(Gs + row * 64 + ((kc ^ (row & 7)) * 8));
        sv = __builtin_amdgcn_mfma_f32_32x32x16_f16(a, Bi[kf], sv, 0, 0, 0);
      }
      // P = 256*sigmoid => rcp(2^(-arg-8) + 2^-8)
      float pv[16];
      float dps = 0.0f;
#pragma unroll
      for (int r = 0; r < 16; ++r) {
        float ap = fmaf(negs2, sv[r], cin) + cjn[r];
        float e2 = __builtin_amdgcn_exp2f(ap);
        float adj = __builtin_amdgcn_rcpf(e2 + 0.00390625f);
        dps += adj;
        pv[r] = adj;
      }
      dp += dps;
      // P^T -> B-frags (pack + half-wave exchange), then O^T += H^T * P^T
#pragma unroll
      for (int kq = 0; kq < 2; ++kq) {
        int q = kq * 8;
        uint32 lo0 = pack2h(pv[q + 0], pv[q + 1]);
        uint32 lo1 = pack2h(pv[q + 2], pv[q + 3]);
        uint32 hi0 = pack2h(pv[q + 4], pv[q + 5]);
        uint32 hi1 = pack2h(pv[q + 6], pv[q + 7]);
        uint32 sl0 = (uint32)__shfl_xor((int)lo0, 32, 64);
        uint32 sl1 = (uint32)__shfl_xor((int)lo1, 32, 64);
        uint32 sh0 = (uint32)__shfl_xor((int)hi0, 32, 64);
        uint32 sh1 = (uint32)__shfl_xor((int)hi1, 32, 64);
        union { uint32 u[4]; v8h v; } b;
        b.u[0] = hb ? sh0 : lo0;
        b.u[1] = hb ? sh1 : lo1;
        b.u[2] = hb ? hi0 : sl0;
        b.u[3] = hb ? hi1 : sl1;
        int kc = (jt * 2 + kq) * 2 + hb;
#pragma unroll
        for (int mp = 0; mp < 4; ++mp) {
          int hc = mp * 32 + ln;
          v8h Ah = *(const v8h*)(Hs + hc * 64 + ((kc ^ (hc & 7)) * 8));
          o[mp] = __builtin_amdgcn_mfma_f32_32x32x16_f16(Ah, b.v, o[mp], 0, 0, 0);
        }
      }
    }
  }

  // epilogue: den partial (i on lanes)
  dp += __shfl_xor(dp, 32, 64);
  if (hb == 0) denp[blockIdx.y * NN + iw + ln] = dp;
  // msg partial: transpose 32x32 O^T tiles through LDS, coalesced stores
  __syncthreads();
  float* Tw = ((float*)SM) + w * (32 * 33);
  float* mout = msgp + (size_t)blockIdx.y * NN * HD;
#pragma unroll
  for (int mp = 0; mp < 4; ++mp) {
#pragma unroll
    for (int r = 0; r < 16; ++r) {
      int hl = (r & 3) + 8 * (r >> 2) + 4 * hb;
      Tw[ln * 33 + hl] = o[mp][r];
    }
#pragma unroll
    for (int rr = 0; rr < 16; ++rr) {
      int il = rr * 2 + hb;
      mout[(size_t)(iw + il) * HD + mp * 32 + ln] = Tw[il * 33 + ln];
    }
  }
}

// ---------------------------------------------------------------------------
// final: out = softmax((sum msgp / sum denp) @ out_w + out_b). 16 lanes/row.
// ---------------------------------------------------------------------------
__global__ __launch_bounds__(256) void final_k(
    const float* __restrict__ msgp, const float* __restrict__ denp,
    const void* __restrict__ ow, const void* __restrict__ ob,
    const float* __restrict__ cst, void* __restrict__ out) {
  __shared__ float Ws[1280];
  const int isbf = (cst[0] != 0.0f);
  if (isbf) {
    for (int i = threadIdx.x; i < 1280; i += 256) Ws[i] = bf2f(((const ushort_t*)ow)[i]);
  } else {
    for (int i = threadIdx.x; i < 1280; i += 256) Ws[i] = ((const float*)ow)[i];
  }
  __syncthreads();
  const int l16 = threadIdx.x & 15, grp = threadIdx.x >> 4;
  const int row = blockIdx.x * 16 + grp;
  float d = 0.0f;
#pragma unroll
  for (int js = 0; js < JS; ++js) d += denp[js * NN + row];
  const float rd = __builtin_amdgcn_rcpf(fmaxf(d, 1e-10f));
  float acc[10];
#pragma unroll
  for (int c = 0; c < 10; ++c) acc[c] = 0.0f;
#pragma unroll
  for (int kk = 0; kk < 8; ++kk) {
    int k = kk * 16 + l16;
    float m = 0.0f;
#pragma unroll
    for (int js = 0; js < JS; ++js)
      m += msgp[(size_t)js * NN * HD + (size_t)row * HD + k];
    float xv = m * rd;
    xv = fminf(fmaxf(xv, -1e6f), 1e6f);
#pragma unroll
    for (int c = 0; c < 10; ++c) acc[c] = fmaf(xv, Ws[k * 10 + c], acc[c]);
  }
  float bias[10];
  if (isbf) {
#pragma unroll
    for (int c = 0; c < 10; ++c) bias[c] = bf2f(((const ushort_t*)ob)[c]);
  } else {
#pragma unroll
    for (int c = 0; c < 10; ++c) bias[c] = ((const float*)ob)[c];
  }
#pragma unroll
  for (int c = 0; c < 10; ++c) {
#pragma unroll
    for (int off = 1; off < 16; off <<= 1) acc[c] += __shfl_xor(acc[c], off, 64);
    acc[c] += bias[c];
  }
  float m = acc[0];
#pragma unroll
  for (int c = 1; c < 10; ++c) m = fmaxf(m, acc[c]);
  float s = 0.0f, e[10];
#pragma unroll
  for (int c = 0; c < 10; ++c) {
    e[c] = __builtin_amdgcn_exp2f((acc[c] - m) * 1.44269504088896341f);
    s += e[c];
  }
  float rs = __builtin_amdgcn_rcpf(s);
  float mine = e[0];
#pragma unroll
  for (int c = 1; c < 10; ++c) mine = (l16 == c) ? e[c] : mine;
  if (l16 < 10) {
    float v = mine * rs;
    if (isbf) ((ushort_t*)out)[(size_t)row * 10 + l16] = f2bf(v);
    else ((float*)out)[(size_t)row * 10 + l16] = v;
  }
}

// ---------------------------------------------------------------------------
extern "C" void kernel_launch(void* const* d_in, const int* in_sizes, int n_in,
                              void* d_out, int out_size, void* d_ws,
                              size_t ws_size, hipStream_t stream) {
  const void* feat = d_in[0];
  const void* glw0 = d_in[1];
  const void* glb0 = d_in[2];
  const void* glw1 = d_in[3];
  const void* glb1 = d_in[4];
  const void* gnw0 = d_in[5];
  const void* gnb0 = d_in[6];
  const void* gnw1 = d_in[7];
  const void* gnb1 = d_in[8];
  const void* ow = d_in[9];
  const void* obv = d_in[10];
  const void* temp = d_in[11];
  const void* thet = d_in[12];

  char* ws = (char*)d_ws;
  _Float16* g = (_Float16*)ws;                          // 2 MB
  _Float16* hT = (_Float16*)(ws + (size_t)(2u << 20));  // 4 MB
  float* crow = (float*)(ws + (size_t)(6u << 20));      // 64 KB
  float* cst = (float*)(ws + (size_t)(6u << 20) + (1u << 16));   // 256 B
  float* crow2 = (float*)(ws + (size_t)(6u << 20) + (2u << 16)); // 64 KB
  float* msgp = (float*)(ws + (size_t)(7u << 20));      // 8 x 8 MB = 64 MB
  float* denp = (float*)(ws + (size_t)(71u << 20));     // 8 x 64 KB

  dim3 b256(256);
  detect_k<<<dim3(1), dim3(64), 0, stream>>>(feat, temp, thet, cst);
  // layer 0
  prep_k<1><<<dim3(NN / 4), b256, 0, stream>>>(feat, nullptr, nullptr, glw0,
                                               glb0, gnw0, gnb0, cst, g, hT,
                                               crow, crow2);
  attn_main<<<dim3(NN / BM, JS), b256, 0, stream>>>(g, hT, crow, crow2, cst,
                                                    msgp, denp);
  // layer 1
  prep_k<0><<<dim3(NN / 4), b256, 0, stream>>>(nullptr, msgp, denp, glw1, glb1,
                                               gnw1, gnb1, cst, g, hT, crow,
                                               crow2);
  attn_main<<<dim3(NN / BM, JS), b256, 0, stream>>>(g, hT, crow, crow2, cst,
                                                    msgp, denp);
  // output layer + softmax
  final_k<<<dim3(NN / 16), b256, 0, stream>>>(msgp, denp, ow, obv, cst, d_out);
}

// Round 9
// 1583.217 us; speedup vs baseline: 1.0337x; 1.0337x over previous
//
#include <hip/hip_runtime.h>

#define NN 16384
#define DL 64
#define HD 128
#define BMW 32          // i-rows per wave
#define BM 128          // rows per WG (4 waves x 32)
#define BN 64           // j per iteration
#define JS 8            // j splits -> grid 128 x 8 = 1024 WGs
#define JCH (NN / JS)
#define NITER (JCH / BN)

typedef _Float16 v8h __attribute__((ext_vector_type(8)));
typedef __fp16 v2fp16 __attribute__((ext_vector_type(2)));
typedef float v16f __attribute__((ext_vector_type(16)));
typedef unsigned short ushort_t;
typedef unsigned int uint32;

__device__ __forceinline__ float bf2f(ushort_t v) {
  return __uint_as_float(((uint32)v) << 16);
}
__device__ __forceinline__ ushort_t f2bf(float f) {
  uint32 u = __float_as_uint(f);
  return (ushort_t)((u + 0x7FFFu + ((u >> 16) & 1u)) >> 16);
}
__device__ __forceinline__ uint32 pack2h(float a, float b) {
  union { v2fp16 h; uint32 u; } p;
  p.h = __builtin_amdgcn_cvt_pkrtz(a, b);
  return p.u;
}
__device__ __forceinline__ void gld16(void* lds, const void* gp) {
  __builtin_amdgcn_global_load_lds(
      (const __attribute__((address_space(1))) uint32*)gp,
      (__attribute__((address_space(3))) uint32*)lds, 16, 0, 0);
}

// ---------------------------------------------------------------------------
// detect input dtype (bf16 vs fp32) from feat bit patterns; stash scalars.
// consts: [0]=isbf, [1]=t, [2]=th, [3]=s2
// ---------------------------------------------------------------------------
__global__ void detect_k(const void* __restrict__ feat,
                         const void* __restrict__ temp,
                         const void* __restrict__ theta,
                         float* __restrict__ consts) {
  const int l = threadIdx.x;  // 64 threads
  const ushort_t* u = (const ushort_t*)feat;
  float v0 = fabsf(bf2f(u[2 * l]));
  float v1 = fabsf(bf2f(u[2 * l + 1]));
  int ok = ((v0 > 1e-4f && v0 < 16.0f) ? 1 : 0) +
           ((v1 > 1e-4f && v1 < 16.0f) ? 1 : 0);
#pragma unroll
  for (int off = 1; off < 64; off <<= 1) ok += __shfl_xor(ok, off, 64);
  if (l == 0) {
    int isbf = (ok >= 100) ? 1 : 0;
    float tv, th;
    if (isbf) {
      tv = bf2f(((const ushort_t*)temp)[0]);
      th = bf2f(((const ushort_t*)theta)[0]);
    } else {
      tv = ((const float*)temp)[0];
      th = ((const float*)theta)[0];
    }
    consts[0] = (float)isbf;
    consts[1] = 1.0f + tv;
    consts[2] = 5.0f + th;
    consts[3] = 2.0f * (1.0f + tv) * 1.44269504088896341f;
  }
}

// ---------------------------------------------------------------------------
// prep: g = relu(x@glw+glb) (fp16), hT = (x@gnw+gnb)^T (fp16 [128][N]),
//       crow = (0.5*th - t*sq)*log2e.  One wave per row.
// ---------------------------------------------------------------------------
template <int L0>
__global__ __launch_bounds__(256) void prep_k(
    const void* __restrict__ xb, const float* __restrict__ msgp,
    const float* __restrict__ denp, const void* __restrict__ glw,
    const void* __restrict__ glb, const void* __restrict__ gnw,
    const void* __restrict__ gnb, const float* __restrict__ cst,
    _Float16* __restrict__ g, _Float16* __restrict__ hT,
    float* __restrict__ crow) {
  __shared__ float xr[4][128];
  const int w = threadIdx.x >> 6, l = threadIdx.x & 63;
  const int row = blockIdx.x * 4 + w;
  const int isbf = (cst[0] != 0.0f);
  float x0, x1;
  if (L0) {
    if (isbf) {
      const ushort_t* p = (const ushort_t*)xb;
      x0 = bf2f(p[row * 128 + 2 * l]);
      x1 = bf2f(p[row * 128 + 2 * l + 1]);
    } else {
      const float* p = (const float*)xb;
      x0 = p[row * 128 + 2 * l];
      x1 = p[row * 128 + 2 * l + 1];
    }
  } else {
    float m0 = 0.0f, m1 = 0.0f, d = 0.0f;
#pragma unroll
    for (int js = 0; js < JS; ++js) {
      const float* mp = msgp + (size_t)js * NN * HD + (size_t)row * HD;
      m0 += mp[2 * l];
      m1 += mp[2 * l + 1];
      d += denp[js * NN + row];
    }
    float rd = __builtin_amdgcn_rcpf(fmaxf(d, 1e-10f));
    x0 = fmaxf(m0 * rd, 0.0f);
    x1 = fmaxf(m1 * rd, 0.0f);
  }
  xr[w][2 * l] = x0;
  xr[w][2 * l + 1] = x1;
  __syncthreads();
  float ag = 0.0f, a0 = 0.0f, a1 = 0.0f;
  float bg, b0, b1;
  if (isbf) {
    const ushort_t* Wg = (const ushort_t*)glw;
    const ushort_t* Wn = (const ushort_t*)gnw;
#pragma unroll 8
    for (int k = 0; k < 128; ++k) {
      float xk = xr[w][k];
      ag = fmaf(xk, bf2f(Wg[k * 64 + l]), ag);
      a0 = fmaf(xk, bf2f(Wn[k * 128 + l]), a0);
      a1 = fmaf(xk, bf2f(Wn[k * 128 + 64 + l]), a1);
    }
    bg = bf2f(((const ushort_t*)glb)[l]);
    b0 = bf2f(((const ushort_t*)gnb)[l]);
    b1 = bf2f(((const ushort_t*)gnb)[64 + l]);
  } else {
    const float* Wg = (const float*)glw;
    const float* Wn = (const float*)gnw;
#pragma unroll 8
    for (int k = 0; k < 128; ++k) {
      float xk = xr[w][k];
      ag = fmaf(xk, Wg[k * 64 + l], ag);
      a0 = fmaf(xk, Wn[k * 128 + l], a0);
      a1 = fmaf(xk, Wn[k * 128 + 64 + l], a1);
    }
    bg = ((const float*)glb)[l];
    b0 = ((const float*)gnb)[l];
    b1 = ((const float*)gnb)[64 + l];
  }
  const float t = cst[1];
  const float th = cst[2];
  float gv = fmaxf(ag + bg, 0.0f);
  _Float16 gq = (_Float16)gv;
  g[(size_t)row * DL + l] = gq;
  float gf = (float)gq;
  float sq = gf * gf;
#pragma unroll
  for (int off = 1; off < 64; off <<= 1) sq += __shfl_xor(sq, off, 64);
  if (l == 0) crow[row] = (0.5f * th - t * sq) * 1.44269504088896341f;
  hT[(size_t)l * NN + row] = (_Float16)(a0 + b0);
  hT[(size_t)(l + 64) * NN + row] = (_Float16)(a1 + b1);
}

// ---------------------------------------------------------------------------
// fused sigmoid-attention: msgp[js] = P*H, denp[js] = P*1, P = 256*sigmoid.
// BMW=32 (R5-verified structure); sigmoid fold: 256/(1+2^-a)=rcp(2^(-a-8)+2^-8)
// ---------------------------------------------------------------------------
__global__ __launch_bounds__(256, 3) void attn_main(
    const _Float16* __restrict__ g, const _Float16* __restrict__ hT,
    const float* __restrict__ crow, const float* __restrict__ cst,
    float* __restrict__ msgp, float* __restrict__ denp) {
  // per buffer: Gs 4096 halfs (8KB) + Hs 8192 halfs (16KB); x2 buffers
  __shared__ __align__(16) short SM[2 * 12288];

  const int tid = threadIdx.x;
  const int w = tid >> 6;
  const int l = tid & 63;
  const int ln = l & 31;
  const int hb = l >> 5;
  const int iw = blockIdx.x * BM + w * BMW;
  const int jb = blockIdx.y * JCH;
  const float negs2 = -cst[3];

  // persistent B-operand frags of G_i: B[n=i=lane&31][k=kf*16+hb*8+e]
  v8h Bi[4];
#pragma unroll
  for (int kf = 0; kf < 4; ++kf)
    Bi[kf] = *(const v8h*)(g + (size_t)(iw + ln) * DL + kf * 16 + hb * 8);

  const float cin = -crow[iw + ln] - 8.0f;

  v16f o[4];
#pragma unroll
  for (int mp = 0; mp < 4; ++mp)
#pragma unroll
    for (int r = 0; r < 16; ++r) o[mp][r] = 0.0f;

  float dp = 0.0f;

  auto stage = [&](int p, int j0) {
    char* Gb = (char*)(SM + p * 12288);
    char* Hb = (char*)(SM + p * 12288 + 4096);
#pragma unroll
    for (int oo = 0; oo < 2; ++oo) {
      int c = oo * 256 + tid;
      int jj = c >> 3, pc = c & 7;
      int kc = pc ^ (jj & 7);
      gld16(Gb + (oo * 256 + w * 64) * 16, g + (size_t)(j0 + jj) * DL + kc * 8);
    }
#pragma unroll
    for (int oo = 0; oo < 4; ++oo) {
      int c = oo * 256 + tid;
      int hc = c >> 3, pc = c & 7;
      int jc = pc ^ (hc & 7);
      gld16(Hb + (oo * 256 + w * 64) * 16, hT + (size_t)hc * NN + j0 + jc * 8);
    }
  };

  stage(0, jb);

#pragma unroll 1
  for (int itr = 0; itr < NITER; ++itr) {
    const int j0 = jb + itr * BN;
    const int p = itr & 1;
    __syncthreads();  // drains loads issued a full compute-phase ago
    if (itr + 1 < NITER) stage(p ^ 1, j0 + BN);
    _Float16* Gs = (_Float16*)(SM + p * 12288);
    _Float16* Hs = (_Float16*)(SM + p * 12288 + 4096);

#pragma unroll
    for (int jt = 0; jt < 2; ++jt) {
      float cj[16];
#pragma unroll
      for (int q2 = 0; q2 < 4; ++q2) {
        float4 f4 = *(const float4*)(crow + j0 + jt * 32 + q2 * 8 + 4 * hb);
        cj[q2 * 4 + 0] = f4.x;
        cj[q2 * 4 + 1] = f4.y;
        cj[q2 * 4 + 2] = f4.z;
        cj[q2 * 4 + 3] = f4.w;
      }
      // S^T = G_j * G_i^T
      v16f sv;
#pragma unroll
      for (int r = 0; r < 16; ++r) sv[r] = 0.0f;
#pragma unroll
      for (int kf = 0; kf < 4; ++kf) {
        int row = jt * 32 + ln;
        int kc = kf * 2 + hb;
        v8h a = *(const v8h*)(Gs + row * 64 + ((kc ^ (row & 7)) * 8));
        sv = __builtin_amdgcn_mfma_f32_32x32x16_f16(a, Bi[kf], sv, 0, 0, 0);
      }
      // P = 256*sigmoid => rcp(2^(-arg-8) + 2^-8)
      float pv[16];
      float dps = 0.0f;
#pragma unroll
      for (int r = 0; r < 16; ++r) {
        float ap = fmaf(negs2, sv[r], cin) - cj[r];
        float e2 = __builtin_amdgcn_exp2f(ap);
        float adj = __builtin_amdgcn_rcpf(e2 + 0.00390625f);
        dps += adj;
        pv[r] = adj;
      }
      dp += dps;
      // P^T -> B-frags (pack + half-wave exchange), then O^T += H^T * P^T
#pragma unroll
      for (int kq = 0; kq < 2; ++kq) {
        int q = kq * 8;
        uint32 lo0 = pack2h(pv[q + 0], pv[q + 1]);
        uint32 lo1 = pack2h(pv[q + 2], pv[q + 3]);
        uint32 hi0 = pack2h(pv[q + 4], pv[q + 5]);
        uint32 hi1 = pack2h(pv[q + 6], pv[q + 7]);
        uint32 sl0 = (uint32)__shfl_xor((int)lo0, 32, 64);
        uint32 sl1 = (uint32)__shfl_xor((int)lo1, 32, 64);
        uint32 sh0 = (uint32)__shfl_xor((int)hi0, 32, 64);
        uint32 sh1 = (uint32)__shfl_xor((int)hi1, 32, 64);
        union { uint32 u[4]; v8h v; } b;
        b.u[0] = hb ? sh0 : lo0;
        b.u[1] = hb ? sh1 : lo1;
        b.u[2] = hb ? hi0 : sl0;
        b.u[3] = hb ? hi1 : sl1;
        int kc = (jt * 2 + kq) * 2 + hb;
#pragma unroll
        for (int mp = 0; mp < 4; ++mp) {
          int hc = mp * 32 + ln;
          v8h Ah = *(const v8h*)(Hs + hc * 64 + ((kc ^ (hc & 7)) * 8));
          o[mp] = __builtin_amdgcn_mfma_f32_32x32x16_f16(Ah, b.v, o[mp], 0, 0, 0);
        }
      }
    }
  }

  // epilogue: den partial (i on lanes)
  dp += __shfl_xor(dp, 32, 64);
  if (hb == 0) denp[blockIdx.y * NN + iw + ln] = dp;
  // msg partial: transpose 32x32 O^T tiles through LDS, coalesced stores
  __syncthreads();
  float* Tw = ((float*)SM) + w * (32 * 33);
  float* mout = msgp + (size_t)blockIdx.y * NN * HD;
#pragma unroll
  for (int mp = 0; mp < 4; ++mp) {
#pragma unroll
    for (int r = 0; r < 16; ++r) {
      int hl = (r & 3) + 8 * (r >> 2) + 4 * hb;
      Tw[ln * 33 + hl] = o[mp][r];
    }
#pragma unroll
    for (int rr = 0; rr < 16; ++rr) {
      int il = rr * 2 + hb;
      mout[(size_t)(iw + il) * HD + mp * 32 + ln] = Tw[il * 33 + ln];
    }
  }
}

// ---------------------------------------------------------------------------
// final: out = softmax((sum msgp / sum denp) @ out_w + out_b). 16 lanes/row.
// ---------------------------------------------------------------------------
__global__ __launch_bounds__(256) void final_k(
    const float* __restrict__ msgp, const float* __restrict__ denp,
    const void* __restrict__ ow, const void* __restrict__ ob,
    const float* __restrict__ cst, void* __restrict__ out) {
  __shared__ float Ws[1280];
  const int isbf = (cst[0] != 0.0f);
  if (isbf) {
    for (int i = threadIdx.x; i < 1280; i += 256) Ws[i] = bf2f(((const ushort_t*)ow)[i]);
  } else {
    for (int i = threadIdx.x; i < 1280; i += 256) Ws[i] = ((const float*)ow)[i];
  }
  __syncthreads();
  const int l16 = threadIdx.x & 15, grp = threadIdx.x >> 4;
  const int row = blockIdx.x * 16 + grp;
  float d = 0.0f;
#pragma unroll
  for (int js = 0; js < JS; ++js) d += denp[js * NN + row];
  const float rd = __builtin_amdgcn_rcpf(fmaxf(d, 1e-10f));
  float acc[10];
#pragma unroll
  for (int c = 0; c < 10; ++c) acc[c] = 0.0f;
#pragma unroll
  for (int kk = 0; kk < 8; ++kk) {
    int k = kk * 16 + l16;
    float m = 0.0f;
#pragma unroll
    for (int js = 0; js < JS; ++js)
      m += msgp[(size_t)js * NN * HD + (size_t)row * HD + k];
    float xv = m * rd;
    xv = fminf(fmaxf(xv, -1e6f), 1e6f);
#pragma unroll
    for (int c = 0; c < 10; ++c) acc[c] = fmaf(xv, Ws[k * 10 + c], acc[c]);
  }
  float bias[10];
  if (isbf) {
#pragma unroll
    for (int c = 0; c < 10; ++c) bias[c] = bf2f(((const ushort_t*)ob)[c]);
  } else {
#pragma unroll
    for (int c = 0; c < 10; ++c) bias[c] = ((const float*)ob)[c];
  }
#pragma unroll
  for (int c = 0; c < 10; ++c) {
#pragma unroll
    for (int off = 1; off < 16; off <<= 1) acc[c] += __shfl_xor(acc[c], off, 64);
    acc[c] += bias[c];
  }
  float m = acc[0];
#pragma unroll
  for (int c = 1; c < 10; ++c) m = fmaxf(m, acc[c]);
  float s = 0.0f, e[10];
#pragma unroll
  for (int c = 0; c < 10; ++c) {
    e[c] = __builtin_amdgcn_exp2f((acc[c] - m) * 1.44269504088896341f);
    s += e[c];
  }
  float rs = __builtin_amdgcn_rcpf(s);
  float mine = e[0];
#pragma unroll
  for (int c = 1; c < 10; ++c) mine = (l16 == c) ? e[c] : mine;
  if (l16 < 10) {
    float v = mine * rs;
    if (isbf) ((ushort_t*)out)[(size_t)row * 10 + l16] = f2bf(v);
    else ((float*)out)[(size_t)row * 10 + l16] = v;
  }
}

// ---------------------------------------------------------------------------
extern "C" void kernel_launch(void* const* d_in, const int* in_sizes, int n_in,
                              void* d_out, int out_size, void* d_ws,
                              size_t ws_size, hipStream_t stream) {
  const void* feat = d_in[0];
  const void* glw0 = d_in[1];
  const void* glb0 = d_in[2];
  const void* glw1 = d_in[3];
  const void* glb1 = d_in[4];
  const void* gnw0 = d_in[5];
  const void* gnb0 = d_in[6];
  const void* gnw1 = d_in[7];
  const void* gnb1 = d_in[8];
  const void* ow = d_in[9];
  const void* obv = d_in[10];
  const void* temp = d_in[11];
  const void* thet = d_in[12];

  char* ws = (char*)d_ws;
  _Float16* g = (_Float16*)ws;                          // 2 MB
  _Float16* hT = (_Float16*)(ws + (size_t)(2u << 20));  // 4 MB
  float* crow = (float*)(ws + (size_t)(6u << 20));      // 64 KB
  float* cst = (float*)(ws + (size_t)(6u << 20) + (1u << 16));  // 256 B
  float* msgp = (float*)(ws + (size_t)(7u << 20));      // 8 x 8 MB = 64 MB
  float* denp = (float*)(ws + (size_t)(71u << 20));     // 8 x 64 KB

  dim3 b256(256);
  detect_k<<<dim3(1), dim3(64), 0, stream>>>(feat, temp, thet, cst);
  // layer 0
  prep_k<1><<<dim3(NN / 4), b256, 0, stream>>>(feat, nullptr, nullptr, glw0,
                                               glb0, gnw0, gnb0, cst, g, hT,
                                               crow);
  attn_main<<<dim3(NN / BM, JS), b256, 0, stream>>>(g, hT, crow, cst, msgp,
                                                    denp);
  // layer 1
  prep_k<0><<<dim3(NN / 4), b256, 0, stream>>>(nullptr, msgp, denp, glw1, glb1,
                                               gnw1, gnb1, cst, g, hT, crow);
  attn_main<<<dim3(NN / BM, JS), b256, 0, stream>>>(g, hT, crow, cst, msgp,
                                                    denp);
  // output layer + softmax
  final_k<<<dim3(NN / 16), b256, 0, stream>>>(msgp, denp, ow, obv, cst, d_out);
}